// Round 4
// baseline (178.716 us; speedup 1.0000x reference)
//
#include <hip/hip_runtime.h>
#include <stdint.h>

// MoE: D=1024, N=8 experts, top-1 routed (experts 0..6) + shared expert 7,
// gates are exactly 1.0. M=2048 tokens, H=2048.

typedef __bf16 bf16x8 __attribute__((ext_vector_type(8)));
typedef float f32x4 __attribute__((ext_vector_type(4)));
typedef unsigned short ushort8 __attribute__((ext_vector_type(8)));

typedef __attribute__((address_space(1))) const void gvoid_t;
typedef __attribute__((address_space(3))) void lvoid_t;

__device__ __forceinline__ void gload16(void* lds, const void* g) {
  __builtin_amdgcn_global_load_lds((gvoid_t*)g, (lvoid_t*)lds, 16, 0, 0);
}

__device__ __forceinline__ uint16_t f2bf(float f) {
  union { float f; uint32_t u; } v; v.f = f;
  uint32_t u = v.u + 0x7fffu + ((v.u >> 16) & 1u);  // RNE
  return (uint16_t)(u >> 16);
}

#define S_VMCNT8() asm volatile("s_waitcnt vmcnt(8)" ::: "memory")
#define S_VMCNT0() asm volatile("s_waitcnt vmcnt(0)" ::: "memory")
#define S_LGKM0()  asm volatile("s_waitcnt lgkmcnt(0)" ::: "memory")
#define S_BAR()    __builtin_amdgcn_s_barrier()

// ------- register 8x8 transpose+convert: [E][R][C] f32 -> [E][C][R] bf16 -------
// 256 threads, tile 64 rows x 256 cols; thread t: colgrp=t>>3, rowgrp=t&7.
// No LDS, no barriers; reads 256B/row segments, writes 128B/column segments.
__global__ __launch_bounds__(256) void tcvt_all(const float* __restrict__ W1,
                                                const float* __restrict__ W2,
                                                uint16_t* __restrict__ w1t,
                                                uint16_t* __restrict__ w2t) {
  int b = blockIdx.x;
  const float* s; uint16_t* d; int R, C, r0, c0;
  if (b < 2048) {                       // W1: 8 experts x (16 rowtiles x 16 coltiles)
    int e = b >> 8, bb = b & 255;
    R = 1024; C = 4096;
    r0 = (bb & 15) * 64; c0 = (bb >> 4) * 256;
    s = W1 + (size_t)e * R * C;
    d = w1t + (size_t)e * R * C;
  } else {                              // W2: 8 experts x (32 rowtiles x 4 coltiles)
    int x2 = b - 2048;
    int e = x2 >> 7, bb = x2 & 127;
    R = 2048; C = 1024;
    r0 = (bb & 31) * 64; c0 = (bb >> 5) * 256;
    s = W2 + (size_t)e * R * C;
    d = w2t + (size_t)e * R * C;
  }
  int t = threadIdx.x, cg = t >> 3, rg = t & 7;
  int r = r0 + rg * 8, c = c0 + cg * 8;
  const float* sp = s + (size_t)r * C + c;
  uint16_t u[8][8];
#pragma unroll
  for (int i = 0; i < 8; ++i) {
    float4 a = *reinterpret_cast<const float4*>(sp + (size_t)i * C);
    float4 b4 = *reinterpret_cast<const float4*>(sp + (size_t)i * C + 4);
    u[i][0] = f2bf(a.x);  u[i][1] = f2bf(a.y);  u[i][2] = f2bf(a.z);  u[i][3] = f2bf(a.w);
    u[i][4] = f2bf(b4.x); u[i][5] = f2bf(b4.y); u[i][6] = f2bf(b4.z); u[i][7] = f2bf(b4.w);
  }
#pragma unroll
  for (int j = 0; j < 8; ++j) {
    ushort8 o;
#pragma unroll
    for (int i = 0; i < 8; ++i) o[i] = u[i][j];
    *reinterpret_cast<ushort8*>(d + (size_t)(c + j) * R + r) = o;
  }
}

// ---------------- gating + x->bf16 convert fused (no atomics) ----------------
__global__ __launch_bounds__(256) void gate_kernel(const float* __restrict__ x,
                                                   const float* __restrict__ Wg,
                                                   uint16_t* __restrict__ xbf,
                                                   int* __restrict__ idx) {
  int wid = threadIdx.x >> 6, lane = threadIdx.x & 63;
  int m = blockIdx.x * 4 + wid;
  const float* xr = x + (size_t)m * 1024;
  uint16_t* xbr = xbf + (size_t)m * 1024;
  float acc[8] = {0.f, 0.f, 0.f, 0.f, 0.f, 0.f, 0.f, 0.f};
  for (int it = 0; it < 4; ++it) {
    int dbase = it * 256 + lane * 4;
    float4 xv = *reinterpret_cast<const float4*>(xr + dbase);
    ushort4 o;
    o.x = f2bf(xv.x); o.y = f2bf(xv.y); o.z = f2bf(xv.z); o.w = f2bf(xv.w);
    *reinterpret_cast<ushort4*>(xbr + dbase) = o;
    const float* xp = reinterpret_cast<const float*>(&xv);
    for (int dd = 0; dd < 4; ++dd) {
      float xs = xp[dd];
      float4 w0 = *reinterpret_cast<const float4*>(Wg + (size_t)(dbase + dd) * 8);
      float4 w1 = *reinterpret_cast<const float4*>(Wg + (size_t)(dbase + dd) * 8 + 4);
      acc[0] += xs * w0.x; acc[1] += xs * w0.y; acc[2] += xs * w0.z; acc[3] += xs * w0.w;
      acc[4] += xs * w1.x; acc[5] += xs * w1.y; acc[6] += xs * w1.z; acc[7] += xs * w1.w;
    }
  }
  for (int j = 0; j < 7; ++j)
    for (int off = 32; off; off >>= 1)
      acc[j] += __shfl_xor(acc[j], off);
  if (lane == 0) {
    int best = 0; float bv = acc[0];
    for (int j = 1; j < 7; ++j) if (acc[j] > bv) { bv = acc[j]; best = j; }
    idx[m] = best;
  }
}

// -------- single-block stable counting sort: offsets, rowmap, tokrow --------
__global__ __launch_bounds__(256) void compact_kernel(const int* __restrict__ idx,
                                                      int* __restrict__ soff,
                                                      int* __restrict__ scnt,
                                                      int* __restrict__ rowmap,
                                                      int* __restrict__ tokrow) {
  __shared__ int hist[256][7];
  __shared__ int cnts[7];
  __shared__ int off[7];
  int t = threadIdx.x;
  int e8[8];
  int lh[7] = {0, 0, 0, 0, 0, 0, 0};
#pragma unroll
  for (int i = 0; i < 8; ++i) { int e = idx[t * 8 + i]; e8[i] = e; lh[e]++; }
#pragma unroll
  for (int e = 0; e < 7; ++e) hist[t][e] = lh[e];
  __syncthreads();
  if (t < 7) {
    int run = 0;
    for (int i = 0; i < 256; ++i) { int v = hist[i][t]; hist[i][t] = run; run += v; }
    cnts[t] = run;
  }
  __syncthreads();
  if (t == 0) {
    int run = 0;
    for (int e = 0; e < 7; ++e) { off[e] = run; soff[e] = run; scnt[e] = cnts[e]; run += cnts[e]; }
    soff[7] = 0; scnt[7] = 2048;
  }
  __syncthreads();
  int pos[7];
#pragma unroll
  for (int e = 0; e < 7; ++e) pos[e] = off[e] + hist[t][e];
#pragma unroll
  for (int i = 0; i < 8; ++i) {
    int m = t * 8 + i, e = e8[i];
    int r = pos[e]++;
    rowmap[r] = m;
    tokrow[m] = r;
  }
}

// ---------------- FFN1: h = silu(x@W1_b) * (x@W1_a) ----------------
__global__ __launch_bounds__(256, 2) void ffn1_kernel(
    const uint16_t* __restrict__ xbf,   // [2048][1024] bf16
    const uint16_t* __restrict__ w1t,   // [8][4096][1024] bf16 ([n][d])
    const int* __restrict__ soff, const int* __restrict__ scnt,
    const int* __restrict__ rowmap,
    uint16_t* __restrict__ h)           // [4096 compact rows][2048] bf16
{
  int by = blockIdx.y;
  int seg, rt;
  if (by < 42) { seg = by / 6; rt = by % 6; } else { seg = 7; rt = by - 42; }
  int cnt = scnt[seg];
  if (rt * 128 >= cnt) return;
  int base = (seg == 7) ? 2048 : soff[seg];
  int rbase = (seg == 7) ? 0 : soff[seg];
  int n0 = blockIdx.x * 64;

  __shared__ uint16_t lds[2][16384];  // As[128][64]@0, Ba[64][64]@8192, Bb@12288

  int t = threadIdx.x, lane = t & 63, w = t >> 6;
  int trow = w * 8 + ((t >> 3) & 7);
  int slot = (t & 7) ^ (trow & 7);

  const uint16_t* w1e = w1t + (size_t)seg * (4096u * 1024u);
  const uint16_t* aptr[4];
#pragma unroll
  for (int i = 0; i < 4; ++i) {
    int rl = i * 32 + trow;
    int rr = rt * 128 + rl; if (rr >= cnt) rr = cnt - 1;
    int tok = (seg == 7) ? rr : rowmap[rbase + rr];
    aptr[i] = xbf + (size_t)tok * 1024 + slot * 8;
  }
  const uint16_t* baptr[2]; const uint16_t* bbptr[2];
#pragma unroll
  for (int i = 0; i < 2; ++i) {
    int cl = i * 32 + trow;
    baptr[i] = w1e + (size_t)(n0 + cl) * 1024 + slot * 8;
    bbptr[i] = w1e + (size_t)(2048 + n0 + cl) * 1024 + slot * 8;
  }

  auto stage = [&](int buf, int kt) {
    int k0 = kt * 64;
    uint16_t* L = lds[buf];
#pragma unroll
    for (int i = 0; i < 4; ++i) gload16(&L[(i * 32 + trow) * 64 + (t & 7) * 8], aptr[i] + k0);
#pragma unroll
    for (int i = 0; i < 2; ++i) gload16(&L[8192 + (i * 32 + trow) * 64 + (t & 7) * 8], baptr[i] + k0);
#pragma unroll
    for (int i = 0; i < 2; ++i) gload16(&L[12288 + (i * 32 + trow) * 64 + (t & 7) * 8], bbptr[i] + k0);
  };

  int wr = (w >> 1) & 1, wc = w & 1;
  int l15 = lane & 15, lk = lane >> 4;
  f32x4 acca[4][2] = {};
  f32x4 accb[4][2] = {};

  stage(0, 0);
  stage(1, 1);
  for (int kt = 0; kt < 16; ++kt) {
    if (kt < 15) S_VMCNT8(); else S_VMCNT0();
    S_BAR();
    const uint16_t* L = lds[kt & 1];
#pragma unroll
    for (int g = 0; g < 2; ++g) {
      __builtin_amdgcn_s_setprio(1);
      bf16x8 af[4];
#pragma unroll
      for (int m = 0; m < 4; ++m) {
        int row = wr * 64 + m * 16 + l15;
        int p = (g * 4 + lk) ^ (row & 7);
        af[m] = *reinterpret_cast<const bf16x8*>(&L[row * 64 + p * 8]);
      }
#pragma unroll
      for (int n = 0; n < 2; ++n) {
        int ca = wc * 32 + n * 16 + l15;
        int p = (g * 4 + lk) ^ (ca & 7);
        bf16x8 ba = *reinterpret_cast<const bf16x8*>(&L[8192 + ca * 64 + p * 8]);
        bf16x8 bb = *reinterpret_cast<const bf16x8*>(&L[12288 + ca * 64 + p * 8]);
#pragma unroll
        for (int m = 0; m < 4; ++m) {
          acca[m][n] = __builtin_amdgcn_mfma_f32_16x16x32_bf16(af[m], ba, acca[m][n], 0, 0, 0);
          accb[m][n] = __builtin_amdgcn_mfma_f32_16x16x32_bf16(af[m], bb, accb[m][n], 0, 0, 0);
        }
      }
      __builtin_amdgcn_s_setprio(0);
    }
    S_LGKM0();
    S_BAR();
    if (kt < 14) stage(kt & 1, kt + 2);
  }

#pragma unroll
  for (int m = 0; m < 4; ++m)
#pragma unroll
    for (int n = 0; n < 2; ++n) {
      int col = n0 + wc * 32 + n * 16 + l15;
#pragma unroll
      for (int j = 0; j < 4; ++j) {
        int row = rt * 128 + wr * 64 + m * 16 + lk * 4 + j;
        if (row < cnt) {
          float a = acca[m][n][j], b = accb[m][n][j];
          float sv = b / (1.0f + __expf(-b));
          h[(size_t)(base + row) * 2048 + col] = f2bf(sv * a);
        }
      }
    }
}

// ---------------- FFN2: compact rows @ W2; shared->y, routed->yr ----------------
__global__ __launch_bounds__(256, 2) void ffn2_kernel(
    const uint16_t* __restrict__ h,    // [4096][2048] bf16
    const uint16_t* __restrict__ w2t,  // [8][1024][2048] bf16 ([dout][h])
    const int* __restrict__ soff, const int* __restrict__ scnt,
    float* __restrict__ y,             // [2048][1024] f32 (shared expert, SET)
    float* __restrict__ yr)            // [2048][1024] f32 (routed compact, SET)
{
  int by = blockIdx.y;
  int seg, rt;
  if (by < 42) { seg = by / 6; rt = by % 6; } else { seg = 7; rt = by - 42; }
  int cnt = scnt[seg];
  if (rt * 128 >= cnt) return;
  int base = (seg == 7) ? 2048 : soff[seg];
  int obase = (seg == 7) ? 0 : soff[seg];
  int n0 = blockIdx.x * 128;

  __shared__ uint16_t lds[2][16384];  // As[128][64]@0, Bs[128][64]@8192

  int t = threadIdx.x, lane = t & 63, w = t >> 6;
  int trow = w * 8 + ((t >> 3) & 7);
  int slot = (t & 7) ^ (trow & 7);

  const uint16_t* w2e = w2t + (size_t)seg * (1024u * 2048u);
  const uint16_t* aptr[4]; const uint16_t* bptr[4];
#pragma unroll
  for (int i = 0; i < 4; ++i) {
    int rl = i * 32 + trow;
    int rr = rt * 128 + rl; if (rr >= cnt) rr = cnt - 1;
    aptr[i] = h + (size_t)(base + rr) * 2048 + slot * 8;
    bptr[i] = w2e + (size_t)(n0 + rl) * 2048 + slot * 8;
  }

  auto stage = [&](int buf, int kt) {
    int k0 = kt * 64;
    uint16_t* L = lds[buf];
#pragma unroll
    for (int i = 0; i < 4; ++i) gload16(&L[(i * 32 + trow) * 64 + (t & 7) * 8], aptr[i] + k0);
#pragma unroll
    for (int i = 0; i < 4; ++i) gload16(&L[8192 + (i * 32 + trow) * 64 + (t & 7) * 8], bptr[i] + k0);
  };

  int wr = (w >> 1) & 1, wc = w & 1;
  int l15 = lane & 15, lk = lane >> 4;
  f32x4 acc[4][4] = {};

  stage(0, 0);
  stage(1, 1);
  for (int kt = 0; kt < 32; ++kt) {
    if (kt < 31) S_VMCNT8(); else S_VMCNT0();
    S_BAR();
    const uint16_t* L = lds[kt & 1];
#pragma unroll
    for (int g = 0; g < 2; ++g) {
      __builtin_amdgcn_s_setprio(1);
      bf16x8 af[4];
#pragma unroll
      for (int m = 0; m < 4; ++m) {
        int row = wr * 64 + m * 16 + l15;
        int p = (g * 4 + lk) ^ (row & 7);
        af[m] = *reinterpret_cast<const bf16x8*>(&L[row * 64 + p * 8]);
      }
#pragma unroll
      for (int n = 0; n < 4; ++n) {
        int cb = wc * 64 + n * 16 + l15;
        int p = (g * 4 + lk) ^ (cb & 7);
        bf16x8 bfr = *reinterpret_cast<const bf16x8*>(&L[8192 + cb * 64 + p * 8]);
#pragma unroll
        for (int m = 0; m < 4; ++m)
          acc[m][n] = __builtin_amdgcn_mfma_f32_16x16x32_bf16(af[m], bfr, acc[m][n], 0, 0, 0);
      }
      __builtin_amdgcn_s_setprio(0);
    }
    S_LGKM0();
    S_BAR();
    if (kt < 30) stage(kt & 1, kt + 2);
  }

#pragma unroll
  for (int m = 0; m < 4; ++m)
#pragma unroll
    for (int n = 0; n < 4; ++n) {
      int col = n0 + wc * 64 + n * 16 + l15;
#pragma unroll
      for (int j = 0; j < 4; ++j) {
        int row = rt * 128 + wr * 64 + m * 16 + lk * 4 + j;
        if (row < cnt) {
          if (seg == 7) y[(size_t)row * 1024 + col] = acc[m][n][j];
          else          yr[(size_t)(obase + row) * 1024 + col] = acc[m][n][j];
        }
      }
    }
}

// ---------------- combine: y[m] += yr[tokrow[m]] ----------------
__global__ __launch_bounds__(256) void combine_kernel(const float* __restrict__ yr,
                                                      const int* __restrict__ tokrow,
                                                      float* __restrict__ y) {
  int m = blockIdx.x;
  int d = threadIdx.x * 4;
  int r = tokrow[m];
  float4 a = *reinterpret_cast<const float4*>(yr + (size_t)r * 1024 + d);
  float4 o = *reinterpret_cast<const float4*>(y + (size_t)m * 1024 + d);
  o.x += a.x; o.y += a.y; o.z += a.z; o.w += a.w;
  *reinterpret_cast<float4*>(y + (size_t)m * 1024 + d) = o;
}

extern "C" void kernel_launch(void* const* d_in, const int* in_sizes, int n_in,
                              void* d_out, int out_size, void* d_ws, size_t ws_size,
                              hipStream_t stream)
{
  const float* x   = (const float*)d_in[0];   // [2048][1024]
  const float* Wg  = (const float*)d_in[1];   // [1024][8]
  const float* Wl1 = (const float*)d_in[2];   // [8][1024][4096]
  const float* Wl2 = (const float*)d_in[3];   // [8][2048][1024]
  float* y = (float*)d_out;                   // [2048][1024]
  char* ws = (char*)d_ws;

  // ws layout. yr overlays w1t (dead after ffn1).
  uint16_t* xbf = (uint16_t*)(ws);                    //  4 MiB
  uint16_t* w1t = (uint16_t*)(ws + (4ull  << 20));    // 64 MiB
  float*    yr  = (float*)   (ws + (4ull  << 20));    //  8 MiB (overlay)
  uint16_t* w2t = (uint16_t*)(ws + (68ull << 20));    // 32 MiB
  uint16_t* h   = (uint16_t*)(ws + (100ull << 20));   // 16 MiB
  int* idx    = (int*)(ws + (116ull << 20));
  int* tokrow = idx + 2048;
  int* soff   = tokrow + 2048;
  int* scnt   = soff + 8;
  int* rowmap = scnt + 8;  // 2048 ints

  gate_kernel<<<512, 256, 0, stream>>>(x, Wg, xbf, idx);
  compact_kernel<<<1, 256, 0, stream>>>(idx, soff, scnt, rowmap, tokrow);
  tcvt_all<<<3072, 256, 0, stream>>>(Wl1, Wl2, w1t, w2t);
  ffn1_kernel<<<dim3(32, 58), 256, 0, stream>>>(xbf, w1t, soff, scnt, rowmap, h);
  ffn2_kernel<<<dim3(8, 58), 256, 0, stream>>>(h, w2t, soff, scnt, y, yr);
  combine_kernel<<<2048, 256, 0, stream>>>(yr, tokrow, y);
}

// Round 5
// 131.134 us; speedup vs baseline: 1.3628x; 1.3628x over previous
//
#include <hip/hip_runtime.h>
#include <stdint.h>

// MoE: D=1024, N=8 experts, top-1 routed (experts 0..6) + shared expert 7,
// gates are exactly 1.0. M=2048 tokens, H=2048.
// Weights consumed DIRECTLY in natural f32 [k][n] layout (no transpose pass):
// B operand is reg-staged (float4 loads along k), cvt_pk'd to bf16, and
// ds_written into k-slab LDS layout: addr = kg*2048B + swz(col)*16B,
// swz(col) = col ^ ((col>>2)&7)  (bank-floor on both write and frag-read).

typedef __bf16 bf16x8 __attribute__((ext_vector_type(8)));
typedef float f32x4 __attribute__((ext_vector_type(4)));

typedef __attribute__((address_space(1))) const void gvoid_t;
typedef __attribute__((address_space(3))) void lvoid_t;

__device__ __forceinline__ void gload16(void* lds, const void* g) {
  __builtin_amdgcn_global_load_lds((gvoid_t*)g, (lvoid_t*)lds, 16, 0, 0);
}

__device__ __forceinline__ uint16_t f2bf(float f) {
  union { float f; uint32_t u; } v; v.f = f;
  uint32_t u = v.u + 0x7fffu + ((v.u >> 16) & 1u);  // RNE
  return (uint16_t)(u >> 16);
}

#define S_VMCNT12() asm volatile("s_waitcnt vmcnt(12)" ::: "memory")
#define S_VMCNT0()  asm volatile("s_waitcnt vmcnt(0)" ::: "memory")
#define S_LGKM0()   asm volatile("s_waitcnt lgkmcnt(0)" ::: "memory")
#define S_BAR()     __builtin_amdgcn_s_barrier()

#define CVT_PK(dst, lo, hi) \
  asm("v_cvt_pk_bf16_f32 %0, %1, %2" : "=v"(dst) : "v"(lo), "v"(hi))

// ---------------- gating + x->bf16 convert fused (no atomics) ----------------
__global__ __launch_bounds__(256) void gate_kernel(const float* __restrict__ x,
                                                   const float* __restrict__ Wg,
                                                   uint16_t* __restrict__ xbf,
                                                   int* __restrict__ idx) {
  int wid = threadIdx.x >> 6, lane = threadIdx.x & 63;
  int m = blockIdx.x * 4 + wid;
  const float* xr = x + (size_t)m * 1024;
  uint16_t* xbr = xbf + (size_t)m * 1024;
  float acc[8] = {0.f, 0.f, 0.f, 0.f, 0.f, 0.f, 0.f, 0.f};
  for (int it = 0; it < 4; ++it) {
    int dbase = it * 256 + lane * 4;
    float4 xv = *reinterpret_cast<const float4*>(xr + dbase);
    ushort4 o;
    o.x = f2bf(xv.x); o.y = f2bf(xv.y); o.z = f2bf(xv.z); o.w = f2bf(xv.w);
    *reinterpret_cast<ushort4*>(xbr + dbase) = o;
    const float* xp = reinterpret_cast<const float*>(&xv);
    for (int dd = 0; dd < 4; ++dd) {
      float xs = xp[dd];
      float4 w0 = *reinterpret_cast<const float4*>(Wg + (size_t)(dbase + dd) * 8);
      float4 w1 = *reinterpret_cast<const float4*>(Wg + (size_t)(dbase + dd) * 8 + 4);
      acc[0] += xs * w0.x; acc[1] += xs * w0.y; acc[2] += xs * w0.z; acc[3] += xs * w0.w;
      acc[4] += xs * w1.x; acc[5] += xs * w1.y; acc[6] += xs * w1.z; acc[7] += xs * w1.w;
    }
  }
  for (int j = 0; j < 7; ++j)
    for (int off = 32; off; off >>= 1)
      acc[j] += __shfl_xor(acc[j], off);
  if (lane == 0) {
    int best = 0; float bv = acc[0];
    for (int j = 1; j < 7; ++j) if (acc[j] > bv) { bv = acc[j]; best = j; }
    idx[m] = best;
  }
}

// -------- single-block stable counting sort: offsets, rowmap, tokrow --------
__global__ __launch_bounds__(256) void compact_kernel(const int* __restrict__ idx,
                                                      int* __restrict__ soff,
                                                      int* __restrict__ scnt,
                                                      int* __restrict__ rowmap,
                                                      int* __restrict__ tokrow) {
  __shared__ int hist[256][7];
  __shared__ int cnts[7];
  __shared__ int off[7];
  int t = threadIdx.x;
  int e8[8];
  int lh[7] = {0, 0, 0, 0, 0, 0, 0};
#pragma unroll
  for (int i = 0; i < 8; ++i) { int e = idx[t * 8 + i]; e8[i] = e; lh[e]++; }
#pragma unroll
  for (int e = 0; e < 7; ++e) hist[t][e] = lh[e];
  __syncthreads();
  if (t < 7) {
    int run = 0;
    for (int i = 0; i < 256; ++i) { int v = hist[i][t]; hist[i][t] = run; run += v; }
    cnts[t] = run;
  }
  __syncthreads();
  if (t == 0) {
    int run = 0;
    for (int e = 0; e < 7; ++e) { off[e] = run; soff[e] = run; scnt[e] = cnts[e]; run += cnts[e]; }
    soff[7] = 0; scnt[7] = 2048;
  }
  __syncthreads();
  int pos[7];
#pragma unroll
  for (int e = 0; e < 7; ++e) pos[e] = off[e] + hist[t][e];
#pragma unroll
  for (int i = 0; i < 8; ++i) {
    int m = t * 8 + i, e = e8[i];
    int r = pos[e]++;
    rowmap[r] = m;
    tokrow[m] = r;
  }
}

// ---------------- FFN1: h = silu(x@W1_b) * (x@W1_a), W1 natural f32 ----------------
// BM=128, BN=64a+64b, BK=64. A: gload_lds dbuf. B: reg-staged f32->bf16, k-slab LDS.
__global__ __launch_bounds__(256, 2) void ffn1_kernel(
    const uint16_t* __restrict__ xbf,   // [2048][1024] bf16
    const float* __restrict__ W1,       // [8][1024][4096] f32 natural
    const int* __restrict__ soff, const int* __restrict__ scnt,
    const int* __restrict__ rowmap,
    uint16_t* __restrict__ h)           // [4096 compact rows][2048] bf16
{
  int by = blockIdx.y;
  int seg, rt;
  if (by < 42) { seg = by / 6; rt = by % 6; } else { seg = 7; rt = by - 42; }
  int cnt = scnt[seg];
  if (rt * 128 >= cnt) return;
  int base = (seg == 7) ? 2048 : soff[seg];
  int rbase = (seg == 7) ? 0 : soff[seg];
  int n0 = blockIdx.x * 64;

  __shared__ uint16_t lds[2][16384];  // per buf: A[128][64]@0 (16KB), B 8 slabs @8192 (16KB)

  int t = threadIdx.x, lane = t & 63, w = t >> 6;
  int trow = w * 8 + ((t >> 3) & 7);
  int slot = (t & 7) ^ (trow & 7);

  // ---- A staging (bf16 gload_lds) ----
  const uint16_t* aptr[4];
#pragma unroll
  for (int i = 0; i < 4; ++i) {
    int rl = i * 32 + trow;
    int rr = rt * 128 + rl; if (rr >= cnt) rr = cnt - 1;
    int tok = (seg == 7) ? rr : rowmap[rbase + rr];
    aptr[i] = xbf + (size_t)tok * 1024 + slot * 8;
  }
  auto stageA = [&](int buf, int kt) {
    uint16_t* L = lds[buf];
#pragma unroll
    for (int i = 0; i < 4; ++i) gload16(&L[(i * 32 + trow) * 64 + (t & 7) * 8], aptr[i] + kt * 64);
  };

  // ---- B staging (f32 natural -> bf16 k-slabs) ----
  const float* w1f = W1 + (size_t)seg * (1024u * 4096u);
  int kg = t >> 5;
  int n4 = (t & 31) * 4;
  int gcol = (n4 < 64) ? (n0 + n4) : (2048 + n0 + n4 - 64);
  const float* bsrc = w1f + (size_t)(kg * 8) * 4096 + gcol;
  int bwoff[4];
#pragma unroll
  for (int j = 0; j < 4; ++j) {
    int cl = n4 + j;
    int sw = cl ^ ((cl >> 2) & 7);
    bwoff[j] = 8192 + kg * 1024 + sw * 8;
  }
  f32x4 breg[8];
  auto issueB = [&](int kt) {
    const float* p = bsrc + (size_t)kt * 64 * 4096;
#pragma unroll
    for (int i = 0; i < 8; ++i) breg[i] = *reinterpret_cast<const f32x4*>(p + (size_t)i * 4096);
  };
  auto writeB = [&](int buf) {
    uint16_t* L = lds[buf];
#pragma unroll
    for (int j = 0; j < 4; ++j) {
      uint32_t p0, p1, p2, p3;
      CVT_PK(p0, breg[0][j], breg[1][j]);
      CVT_PK(p1, breg[2][j], breg[3][j]);
      CVT_PK(p2, breg[4][j], breg[5][j]);
      CVT_PK(p3, breg[6][j], breg[7][j]);
      uint4 v; v.x = p0; v.y = p1; v.z = p2; v.w = p3;
      *reinterpret_cast<uint4*>(&L[bwoff[j]]) = v;
    }
  };

  int wr = (w >> 1) & 1, wc = w & 1;
  int l15 = lane & 15, lk = lane >> 4;
  int boffA[2], boffB[2];
#pragma unroll
  for (int n = 0; n < 2; ++n) {
    int cl = wc * 32 + n * 16 + l15;
    boffA[n] = 8192 + (cl ^ ((cl >> 2) & 7)) * 8;
    cl += 64;
    boffB[n] = 8192 + (cl ^ ((cl >> 2) & 7)) * 8;
  }

  f32x4 acca[4][2] = {};
  f32x4 accb[4][2] = {};

  // prologue: B0, A0, B1, A1; write B0 -> LDS0
  issueB(0); stageA(0, 0);
  writeB(0);
  issueB(1); stageA(1, 1);
  S_LGKM0();

  for (int kt = 0; kt < 16; ++kt) {
    if (kt < 15) S_VMCNT12(); else S_VMCNT0();
    S_BAR();
    const uint16_t* L = lds[kt & 1];
#pragma unroll
    for (int g = 0; g < 2; ++g) {
      __builtin_amdgcn_s_setprio(1);
      bf16x8 af[4];
#pragma unroll
      for (int m = 0; m < 4; ++m) {
        int row = wr * 64 + m * 16 + l15;
        int p = (g * 4 + lk) ^ (row & 7);
        af[m] = *reinterpret_cast<const bf16x8*>(&L[row * 64 + p * 8]);
      }
#pragma unroll
      for (int n = 0; n < 2; ++n) {
        int ks = (g * 4 + lk) * 1024;
        bf16x8 ba = *reinterpret_cast<const bf16x8*>(&L[boffA[n] + ks]);
        bf16x8 bb = *reinterpret_cast<const bf16x8*>(&L[boffB[n] + ks]);
#pragma unroll
        for (int m = 0; m < 4; ++m) {
          acca[m][n] = __builtin_amdgcn_mfma_f32_16x16x32_bf16(af[m], ba, acca[m][n], 0, 0, 0);
          accb[m][n] = __builtin_amdgcn_mfma_f32_16x16x32_bf16(af[m], bb, accb[m][n], 0, 0, 0);
        }
      }
      __builtin_amdgcn_s_setprio(0);
    }
    if (kt < 15) writeB((kt + 1) & 1);
    S_LGKM0();
    S_BAR();
    if (kt < 14) { issueB(kt + 2); stageA(kt & 1, kt + 2); }
  }

#pragma unroll
  for (int m = 0; m < 4; ++m)
#pragma unroll
    for (int n = 0; n < 2; ++n) {
      int col = n0 + wc * 32 + n * 16 + l15;
#pragma unroll
      for (int j = 0; j < 4; ++j) {
        int row = rt * 128 + wr * 64 + m * 16 + lk * 4 + j;
        if (row < cnt) {
          float a = acca[m][n][j], b = accb[m][n][j];
          float sv = b / (1.0f + __expf(-b));
          h[(size_t)(base + row) * 2048 + col] = f2bf(sv * a);
        }
      }
    }
}

// ---------------- FFN2: compact rows @ W2 (natural f32); shared->y, routed->yr ----------------
// BM=128, BN=128, BK=64. Same scheme, NT=32.
__global__ __launch_bounds__(256, 2) void ffn2_kernel(
    const uint16_t* __restrict__ h,    // [4096][2048] bf16
    const float* __restrict__ W2,      // [8][2048][1024] f32 natural
    const int* __restrict__ soff, const int* __restrict__ scnt,
    float* __restrict__ y,             // [2048][1024] f32 (shared expert, SET)
    float* __restrict__ yr)            // [2048][1024] f32 (routed compact, SET)
{
  int by = blockIdx.y;
  int seg, rt;
  if (by < 42) { seg = by / 6; rt = by % 6; } else { seg = 7; rt = by - 42; }
  int cnt = scnt[seg];
  if (rt * 128 >= cnt) return;
  int base = (seg == 7) ? 2048 : soff[seg];
  int obase = (seg == 7) ? 0 : soff[seg];
  int n0 = blockIdx.x * 128;

  __shared__ uint16_t lds[2][16384];  // A[128][64]@0, B 8 slabs @8192

  int t = threadIdx.x, lane = t & 63, w = t >> 6;
  int trow = w * 8 + ((t >> 3) & 7);
  int slot = (t & 7) ^ (trow & 7);

  const uint16_t* aptr[4];
#pragma unroll
  for (int i = 0; i < 4; ++i) {
    int rl = i * 32 + trow;
    int rr = rt * 128 + rl; if (rr >= cnt) rr = cnt - 1;
    aptr[i] = h + (size_t)(base + rr) * 2048 + slot * 8;
  }
  auto stageA = [&](int buf, int kt) {
    uint16_t* L = lds[buf];
#pragma unroll
    for (int i = 0; i < 4; ++i) gload16(&L[(i * 32 + trow) * 64 + (t & 7) * 8], aptr[i] + kt * 64);
  };

  const float* w2f = W2 + (size_t)seg * (2048u * 1024u);
  int kg = t >> 5;
  int n4 = (t & 31) * 4;
  const float* bsrc = w2f + (size_t)(kg * 8) * 1024 + n0 + n4;
  int bwoff[4];
#pragma unroll
  for (int j = 0; j < 4; ++j) {
    int cl = n4 + j;
    int sw = cl ^ ((cl >> 2) & 7);
    bwoff[j] = 8192 + kg * 1024 + sw * 8;
  }
  f32x4 breg[8];
  auto issueB = [&](int kt) {
    const float* p = bsrc + (size_t)kt * 64 * 1024;
#pragma unroll
    for (int i = 0; i < 8; ++i) breg[i] = *reinterpret_cast<const f32x4*>(p + (size_t)i * 1024);
  };
  auto writeB = [&](int buf) {
    uint16_t* L = lds[buf];
#pragma unroll
    for (int j = 0; j < 4; ++j) {
      uint32_t p0, p1, p2, p3;
      CVT_PK(p0, breg[0][j], breg[1][j]);
      CVT_PK(p1, breg[2][j], breg[3][j]);
      CVT_PK(p2, breg[4][j], breg[5][j]);
      CVT_PK(p3, breg[6][j], breg[7][j]);
      uint4 v; v.x = p0; v.y = p1; v.z = p2; v.w = p3;
      *reinterpret_cast<uint4*>(&L[bwoff[j]]) = v;
    }
  };

  int wr = (w >> 1) & 1, wc = w & 1;
  int l15 = lane & 15, lk = lane >> 4;
  int boff[4];
#pragma unroll
  for (int n = 0; n < 4; ++n) {
    int cl = wc * 64 + n * 16 + l15;
    boff[n] = 8192 + (cl ^ ((cl >> 2) & 7)) * 8;
  }

  f32x4 acc[4][4] = {};

  issueB(0); stageA(0, 0);
  writeB(0);
  issueB(1); stageA(1, 1);
  S_LGKM0();

  for (int kt = 0; kt < 32; ++kt) {
    if (kt < 31) S_VMCNT12(); else S_VMCNT0();
    S_BAR();
    const uint16_t* L = lds[kt & 1];
#pragma unroll
    for (int g = 0; g < 2; ++g) {
      __builtin_amdgcn_s_setprio(1);
      bf16x8 af[4];
#pragma unroll
      for (int m = 0; m < 4; ++m) {
        int row = wr * 64 + m * 16 + l15;
        int p = (g * 4 + lk) ^ (row & 7);
        af[m] = *reinterpret_cast<const bf16x8*>(&L[row * 64 + p * 8]);
      }
#pragma unroll
      for (int n = 0; n < 4; ++n) {
        bf16x8 bfr = *reinterpret_cast<const bf16x8*>(&L[boff[n] + (g * 4 + lk) * 1024]);
#pragma unroll
        for (int m = 0; m < 4; ++m)
          acc[m][n] = __builtin_amdgcn_mfma_f32_16x16x32_bf16(af[m], bfr, acc[m][n], 0, 0, 0);
      }
      __builtin_amdgcn_s_setprio(0);
    }
    if (kt < 31) writeB((kt + 1) & 1);
    S_LGKM0();
    S_BAR();
    if (kt < 30) { issueB(kt + 2); stageA(kt & 1, kt + 2); }
  }

#pragma unroll
  for (int m = 0; m < 4; ++m)
#pragma unroll
    for (int n = 0; n < 4; ++n) {
      int col = n0 + wc * 64 + n * 16 + l15;
#pragma unroll
      for (int j = 0; j < 4; ++j) {
        int row = rt * 128 + wr * 64 + m * 16 + lk * 4 + j;
        if (row < cnt) {
          if (seg == 7) y[(size_t)row * 1024 + col] = acc[m][n][j];
          else          yr[(size_t)(obase + row) * 1024 + col] = acc[m][n][j];
        }
      }
    }
}

// ---------------- combine: y[m] += yr[tokrow[m]] ----------------
__global__ __launch_bounds__(256) void combine_kernel(const float* __restrict__ yr,
                                                      const int* __restrict__ tokrow,
                                                      float* __restrict__ y) {
  int m = blockIdx.x;
  int d = threadIdx.x * 4;
  int r = tokrow[m];
  float4 a = *reinterpret_cast<const float4*>(yr + (size_t)r * 1024 + d);
  float4 o = *reinterpret_cast<const float4*>(y + (size_t)m * 1024 + d);
  o.x += a.x; o.y += a.y; o.z += a.z; o.w += a.w;
  *reinterpret_cast<float4*>(y + (size_t)m * 1024 + d) = o;
}

extern "C" void kernel_launch(void* const* d_in, const int* in_sizes, int n_in,
                              void* d_out, int out_size, void* d_ws, size_t ws_size,
                              hipStream_t stream)
{
  const float* x   = (const float*)d_in[0];   // [2048][1024]
  const float* Wg  = (const float*)d_in[1];   // [1024][8]
  const float* Wl1 = (const float*)d_in[2];   // [8][1024][4096]
  const float* Wl2 = (const float*)d_in[3];   // [8][2048][1024]
  float* y = (float*)d_out;                   // [2048][1024]
  char* ws = (char*)d_ws;

  uint16_t* xbf = (uint16_t*)(ws);                    //  4 MiB
  uint16_t* h   = (uint16_t*)(ws + (4ull  << 20));    // 16 MiB
  float*    yr  = (float*)   (ws + (20ull << 20));    //  8 MiB
  int* idx    = (int*)(ws + (28ull << 20));
  int* tokrow = idx + 2048;
  int* soff   = tokrow + 2048;
  int* scnt   = soff + 8;
  int* rowmap = scnt + 8;  // 2048 ints

  gate_kernel<<<512, 256, 0, stream>>>(x, Wg, xbf, idx);
  compact_kernel<<<1, 256, 0, stream>>>(idx, soff, scnt, rowmap, tokrow);
  ffn1_kernel<<<dim3(32, 58), 256, 0, stream>>>(xbf, Wl1, soff, scnt, rowmap, h);
  ffn2_kernel<<<dim3(8, 58), 256, 0, stream>>>(h, Wl2, soff, scnt, y, yr);
  combine_kernel<<<2048, 256, 0, stream>>>(yr, tokrow, y);
}

// Round 6
// 129.412 us; speedup vs baseline: 1.3810x; 1.0133x over previous
//
#include <hip/hip_runtime.h>
#include <stdint.h>

// MoE: D=1024, N=8 experts, top-1 routed (experts 0..6) + shared expert 7,
// gates are exactly 1.0. M=2048 tokens, H=2048.
// Weights consumed DIRECTLY in natural f32 [k][n] layout (no transpose pass).
// B operand: reg-staged f32 loads, cvt_pk -> bf16, ds_write into k-slab LDS.
// Pipeline: TWO breg sets, issue->write distance = 2 iters, counted vmcnt(12).

typedef __bf16 bf16x8 __attribute__((ext_vector_type(8)));
typedef float f32x4 __attribute__((ext_vector_type(4)));

typedef __attribute__((address_space(1))) const void gvoid_t;
typedef __attribute__((address_space(3))) void lvoid_t;

__device__ __forceinline__ void gload16(void* lds, const void* g) {
  __builtin_amdgcn_global_load_lds((gvoid_t*)g, (lvoid_t*)lds, 16, 0, 0);
}

__device__ __forceinline__ uint16_t f2bf(float f) {
  union { float f; uint32_t u; } v; v.f = f;
  uint32_t u = v.u + 0x7fffu + ((v.u >> 16) & 1u);  // RNE
  return (uint16_t)(u >> 16);
}

#define S_VMCNT12() asm volatile("s_waitcnt vmcnt(12)" ::: "memory")
#define S_VMCNT16() asm volatile("s_waitcnt vmcnt(16)" ::: "memory")
#define S_VMCNT0()  asm volatile("s_waitcnt vmcnt(0)" ::: "memory")
#define S_LGKM0()   asm volatile("s_waitcnt lgkmcnt(0)" ::: "memory")
#define S_BAR()     __builtin_amdgcn_s_barrier()

#define CVT_PK(dst, lo, hi) \
  asm("v_cvt_pk_bf16_f32 %0, %1, %2" : "=v"(dst) : "v"(lo), "v"(hi))

// ---------------- gating + x->bf16 convert fused (no atomics) ----------------
__global__ __launch_bounds__(256) void gate_kernel(const float* __restrict__ x,
                                                   const float* __restrict__ Wg,
                                                   uint16_t* __restrict__ xbf,
                                                   int* __restrict__ idx) {
  int wid = threadIdx.x >> 6, lane = threadIdx.x & 63;
  int m = blockIdx.x * 4 + wid;
  const float* xr = x + (size_t)m * 1024;
  uint16_t* xbr = xbf + (size_t)m * 1024;
  float acc[8] = {0.f, 0.f, 0.f, 0.f, 0.f, 0.f, 0.f, 0.f};
  for (int it = 0; it < 4; ++it) {
    int dbase = it * 256 + lane * 4;
    float4 xv = *reinterpret_cast<const float4*>(xr + dbase);
    ushort4 o;
    o.x = f2bf(xv.x); o.y = f2bf(xv.y); o.z = f2bf(xv.z); o.w = f2bf(xv.w);
    *reinterpret_cast<ushort4*>(xbr + dbase) = o;
    const float* xp = reinterpret_cast<const float*>(&xv);
    for (int dd = 0; dd < 4; ++dd) {
      float xs = xp[dd];
      float4 w0 = *reinterpret_cast<const float4*>(Wg + (size_t)(dbase + dd) * 8);
      float4 w1 = *reinterpret_cast<const float4*>(Wg + (size_t)(dbase + dd) * 8 + 4);
      acc[0] += xs * w0.x; acc[1] += xs * w0.y; acc[2] += xs * w0.z; acc[3] += xs * w0.w;
      acc[4] += xs * w1.x; acc[5] += xs * w1.y; acc[6] += xs * w1.z; acc[7] += xs * w1.w;
    }
  }
  for (int j = 0; j < 7; ++j)
    for (int off = 32; off; off >>= 1)
      acc[j] += __shfl_xor(acc[j], off);
  if (lane == 0) {
    int best = 0; float bv = acc[0];
    for (int j = 1; j < 7; ++j) if (acc[j] > bv) { bv = acc[j]; best = j; }
    idx[m] = best;
  }
}

// -------- single-block stable counting sort: offsets, rowmap, tokrow --------
__global__ __launch_bounds__(256) void compact_kernel(const int* __restrict__ idx,
                                                      int* __restrict__ soff,
                                                      int* __restrict__ scnt,
                                                      int* __restrict__ rowmap,
                                                      int* __restrict__ tokrow) {
  __shared__ int hist[256][7];
  __shared__ int cnts[7];
  __shared__ int off[7];
  int t = threadIdx.x;
  int e8[8];
  int lh[7] = {0, 0, 0, 0, 0, 0, 0};
#pragma unroll
  for (int i = 0; i < 8; ++i) { int e = idx[t * 8 + i]; e8[i] = e; lh[e]++; }
#pragma unroll
  for (int e = 0; e < 7; ++e) hist[t][e] = lh[e];
  __syncthreads();
  if (t < 7) {
    int run = 0;
    for (int i = 0; i < 256; ++i) { int v = hist[i][t]; hist[i][t] = run; run += v; }
    cnts[t] = run;
  }
  __syncthreads();
  if (t == 0) {
    int run = 0;
    for (int e = 0; e < 7; ++e) { off[e] = run; soff[e] = run; scnt[e] = cnts[e]; run += cnts[e]; }
    soff[7] = 0; scnt[7] = 2048;
  }
  __syncthreads();
  int pos[7];
#pragma unroll
  for (int e = 0; e < 7; ++e) pos[e] = off[e] + hist[t][e];
#pragma unroll
  for (int i = 0; i < 8; ++i) {
    int m = t * 8 + i, e = e8[i];
    int r = pos[e]++;
    rowmap[r] = m;
    tokrow[m] = r;
  }
}

// ---------------- FFN1: h = silu(x@W1_b) * (x@W1_a), W1 natural f32 ----------------
// BM=128, BN=64a+64b, BK=64. A: gload_lds dbuf (dist 2). B: 2 breg sets (dist 2).
__global__ __launch_bounds__(256, 2) void ffn1_kernel(
    const uint16_t* __restrict__ xbf,   // [2048][1024] bf16
    const float* __restrict__ W1,       // [8][1024][4096] f32 natural
    const int* __restrict__ soff, const int* __restrict__ scnt,
    const int* __restrict__ rowmap,
    uint16_t* __restrict__ h)           // [4096 compact rows][2048] bf16
{
  int by = blockIdx.y;
  int seg, rt;
  if (by < 42) { seg = by / 6; rt = by % 6; } else { seg = 7; rt = by - 42; }
  int cnt = scnt[seg];
  if (rt * 128 >= cnt) return;
  int base = (seg == 7) ? 2048 : soff[seg];
  int rbase = (seg == 7) ? 0 : soff[seg];
  int n0 = blockIdx.x * 64;

  __shared__ uint16_t lds[2][16384];  // per buf: A[128][64]@0 (16KB), B 8 k-slabs @8192 (16KB)

  int t = threadIdx.x, lane = t & 63, w = t >> 6;
  int trow = w * 8 + ((t >> 3) & 7);
  int slot = (t & 7) ^ (trow & 7);

  // ---- A staging (bf16 gload_lds) ----
  const uint16_t* aptr[4];
#pragma unroll
  for (int i = 0; i < 4; ++i) {
    int rl = i * 32 + trow;
    int rr = rt * 128 + rl; if (rr >= cnt) rr = cnt - 1;
    int tok = (seg == 7) ? rr : rowmap[rbase + rr];
    aptr[i] = xbf + (size_t)tok * 1024 + slot * 8;
  }
  auto stageA = [&](int buf, int kt) {
    uint16_t* L = lds[buf];
#pragma unroll
    for (int i = 0; i < 4; ++i) gload16(&L[(i * 32 + trow) * 64 + (t & 7) * 8], aptr[i] + kt * 64);
  };

  // ---- B staging (f32 natural -> bf16 k-slabs), 2 reg sets ----
  const float* w1f = W1 + (size_t)seg * (1024u * 4096u);
  int kg = t >> 5;
  int n4 = (t & 31) * 4;
  int gcol = (n4 < 64) ? (n0 + n4) : (2048 + n0 + n4 - 64);
  const float* bsrc = w1f + (size_t)(kg * 8) * 4096 + gcol;
  int bwoff[4];
#pragma unroll
  for (int j = 0; j < 4; ++j) {
    int cl = n4 + j;
    int sw = cl ^ ((cl >> 2) & 7);
    bwoff[j] = 8192 + kg * 1024 + sw * 8;
  }
  f32x4 P0[8], P1[8];
  auto issueB = [&](f32x4 (&P)[8], int kt) {
    const float* p = bsrc + (size_t)kt * 64 * 4096;
#pragma unroll
    for (int i = 0; i < 8; ++i) P[i] = *reinterpret_cast<const f32x4*>(p + (size_t)i * 4096);
  };
  auto writeB = [&](f32x4 (&P)[8], int buf) {
    uint16_t* L = lds[buf];
#pragma unroll
    for (int j = 0; j < 4; ++j) {
      uint32_t q0, q1, q2, q3;
      CVT_PK(q0, P[0][j], P[1][j]);
      CVT_PK(q1, P[2][j], P[3][j]);
      CVT_PK(q2, P[4][j], P[5][j]);
      CVT_PK(q3, P[6][j], P[7][j]);
      uint4 v; v.x = q0; v.y = q1; v.z = q2; v.w = q3;
      *reinterpret_cast<uint4*>(&L[bwoff[j]]) = v;
    }
  };

  int wr = (w >> 1) & 1, wc = w & 1;
  int l15 = lane & 15, lk = lane >> 4;
  int boffA[2], boffB[2];
#pragma unroll
  for (int n = 0; n < 2; ++n) {
    int cl = wc * 32 + n * 16 + l15;
    boffA[n] = 8192 + (cl ^ ((cl >> 2) & 7)) * 8;
    cl += 64;
    boffB[n] = 8192 + (cl ^ ((cl >> 2) & 7)) * 8;
  }

  f32x4 acca[4][2] = {};
  f32x4 accb[4][2] = {};

  auto compute = [&](int buf) {
    const uint16_t* L = lds[buf];
#pragma unroll
    for (int g = 0; g < 2; ++g) {
      __builtin_amdgcn_s_setprio(1);
      bf16x8 af[4];
#pragma unroll
      for (int m = 0; m < 4; ++m) {
        int row = wr * 64 + m * 16 + l15;
        int p = (g * 4 + lk) ^ (row & 7);
        af[m] = *reinterpret_cast<const bf16x8*>(&L[row * 64 + p * 8]);
      }
#pragma unroll
      for (int n = 0; n < 2; ++n) {
        int ks = (g * 4 + lk) * 1024;
        bf16x8 ba = *reinterpret_cast<const bf16x8*>(&L[boffA[n] + ks]);
        bf16x8 bb = *reinterpret_cast<const bf16x8*>(&L[boffB[n] + ks]);
#pragma unroll
        for (int m = 0; m < 4; ++m) {
          acca[m][n] = __builtin_amdgcn_mfma_f32_16x16x32_bf16(af[m], ba, acca[m][n], 0, 0, 0);
          accb[m][n] = __builtin_amdgcn_mfma_f32_16x16x32_bf16(af[m], bb, accb[m][n], 0, 0, 0);
        }
      }
      __builtin_amdgcn_s_setprio(0);
    }
  };

  const int NT = 16;
  // prologue: issue B0->P0, A0; B1->P1, A1; drain P0; write B0; reissue P0<-B2
  issueB(P0, 0); stageA(0, 0);
  issueB(P1, 1); stageA(1, 1);
  S_VMCNT16();
  writeB(P0, 0);
  issueB(P0, 2);
  S_LGKM0();

#pragma unroll 1
  for (int kt = 0; kt < NT; kt += 2) {
    // ---- even sub-iter: compute buf0, write P1 -> buf1 ----
    if (kt < NT - 2) S_VMCNT12(); else S_VMCNT0();
    S_BAR();
    compute(0);
    if (kt < NT - 1) writeB(P1, 1);
    S_LGKM0(); S_BAR();
    if (kt < NT - 3) issueB(P1, kt + 3);
    if (kt < NT - 2) stageA(0, kt + 2);
    // ---- odd sub-iter: compute buf1, write P0 -> buf0 ----
    int ko = kt + 1;
    if (ko < NT - 2) S_VMCNT12(); else S_VMCNT0();
    S_BAR();
    compute(1);
    if (ko < NT - 1) writeB(P0, 0);
    S_LGKM0(); S_BAR();
    if (ko < NT - 3) issueB(P0, ko + 3);
    if (ko < NT - 2) stageA(1, ko + 2);
  }

#pragma unroll
  for (int m = 0; m < 4; ++m)
#pragma unroll
    for (int n = 0; n < 2; ++n) {
      int col = n0 + wc * 32 + n * 16 + l15;
#pragma unroll
      for (int j = 0; j < 4; ++j) {
        int row = rt * 128 + wr * 64 + m * 16 + lk * 4 + j;
        if (row < cnt) {
          float a = acca[m][n][j], b = accb[m][n][j];
          float sv = b / (1.0f + __expf(-b));
          h[(size_t)(base + row) * 2048 + col] = f2bf(sv * a);
        }
      }
    }
}

// ---------------- FFN2: compact rows @ W2 (natural f32); shared->y, routed->yr ----------------
// BM=128, BN=128, BK=64, NT=32. Same 2-deep pipeline.
__global__ __launch_bounds__(256, 2) void ffn2_kernel(
    const uint16_t* __restrict__ h,    // [4096][2048] bf16
    const float* __restrict__ W2,      // [8][2048][1024] f32 natural
    const int* __restrict__ soff, const int* __restrict__ scnt,
    float* __restrict__ y,             // [2048][1024] f32 (shared expert, SET)
    float* __restrict__ yr)            // [2048][1024] f32 (routed compact, SET)
{
  int by = blockIdx.y;
  int seg, rt;
  if (by < 42) { seg = by / 6; rt = by % 6; } else { seg = 7; rt = by - 42; }
  int cnt = scnt[seg];
  if (rt * 128 >= cnt) return;
  int base = (seg == 7) ? 2048 : soff[seg];
  int obase = (seg == 7) ? 0 : soff[seg];
  int n0 = blockIdx.x * 128;

  __shared__ uint16_t lds[2][16384];  // A[128][64]@0, B 8 k-slabs @8192

  int t = threadIdx.x, lane = t & 63, w = t >> 6;
  int trow = w * 8 + ((t >> 3) & 7);
  int slot = (t & 7) ^ (trow & 7);

  const uint16_t* aptr[4];
#pragma unroll
  for (int i = 0; i < 4; ++i) {
    int rl = i * 32 + trow;
    int rr = rt * 128 + rl; if (rr >= cnt) rr = cnt - 1;
    aptr[i] = h + (size_t)(base + rr) * 2048 + slot * 8;
  }
  auto stageA = [&](int buf, int kt) {
    uint16_t* L = lds[buf];
#pragma unroll
    for (int i = 0; i < 4; ++i) gload16(&L[(i * 32 + trow) * 64 + (t & 7) * 8], aptr[i] + kt * 64);
  };

  const float* w2f = W2 + (size_t)seg * (2048u * 1024u);
  int kg = t >> 5;
  int n4 = (t & 31) * 4;
  const float* bsrc = w2f + (size_t)(kg * 8) * 1024 + n0 + n4;
  int bwoff[4];
#pragma unroll
  for (int j = 0; j < 4; ++j) {
    int cl = n4 + j;
    int sw = cl ^ ((cl >> 2) & 7);
    bwoff[j] = 8192 + kg * 1024 + sw * 8;
  }
  f32x4 P0[8], P1[8];
  auto issueB = [&](f32x4 (&P)[8], int kt) {
    const float* p = bsrc + (size_t)kt * 64 * 1024;
#pragma unroll
    for (int i = 0; i < 8; ++i) P[i] = *reinterpret_cast<const f32x4*>(p + (size_t)i * 1024);
  };
  auto writeB = [&](f32x4 (&P)[8], int buf) {
    uint16_t* L = lds[buf];
#pragma unroll
    for (int j = 0; j < 4; ++j) {
      uint32_t q0, q1, q2, q3;
      CVT_PK(q0, P[0][j], P[1][j]);
      CVT_PK(q1, P[2][j], P[3][j]);
      CVT_PK(q2, P[4][j], P[5][j]);
      CVT_PK(q3, P[6][j], P[7][j]);
      uint4 v; v.x = q0; v.y = q1; v.z = q2; v.w = q3;
      *reinterpret_cast<uint4*>(&L[bwoff[j]]) = v;
    }
  };

  int wr = (w >> 1) & 1, wc = w & 1;
  int l15 = lane & 15, lk = lane >> 4;
  int boff[4];
#pragma unroll
  for (int n = 0; n < 4; ++n) {
    int cl = wc * 64 + n * 16 + l15;
    boff[n] = 8192 + (cl ^ ((cl >> 2) & 7)) * 8;
  }

  f32x4 acc[4][4] = {};

  auto compute = [&](int buf) {
    const uint16_t* L = lds[buf];
#pragma unroll
    for (int g = 0; g < 2; ++g) {
      __builtin_amdgcn_s_setprio(1);
      bf16x8 af[4];
#pragma unroll
      for (int m = 0; m < 4; ++m) {
        int row = wr * 64 + m * 16 + l15;
        int p = (g * 4 + lk) ^ (row & 7);
        af[m] = *reinterpret_cast<const bf16x8*>(&L[row * 64 + p * 8]);
      }
#pragma unroll
      for (int n = 0; n < 4; ++n) {
        bf16x8 bfr = *reinterpret_cast<const bf16x8*>(&L[boff[n] + (g * 4 + lk) * 1024]);
#pragma unroll
        for (int m = 0; m < 4; ++m)
          acc[m][n] = __builtin_amdgcn_mfma_f32_16x16x32_bf16(af[m], bfr, acc[m][n], 0, 0, 0);
      }
      __builtin_amdgcn_s_setprio(0);
    }
  };

  const int NT = 32;
  issueB(P0, 0); stageA(0, 0);
  issueB(P1, 1); stageA(1, 1);
  S_VMCNT16();
  writeB(P0, 0);
  issueB(P0, 2);
  S_LGKM0();

#pragma unroll 1
  for (int kt = 0; kt < NT; kt += 2) {
    if (kt < NT - 2) S_VMCNT12(); else S_VMCNT0();
    S_BAR();
    compute(0);
    if (kt < NT - 1) writeB(P1, 1);
    S_LGKM0(); S_BAR();
    if (kt < NT - 3) issueB(P1, kt + 3);
    if (kt < NT - 2) stageA(0, kt + 2);
    int ko = kt + 1;
    if (ko < NT - 2) S_VMCNT12(); else S_VMCNT0();
    S_BAR();
    compute(1);
    if (ko < NT - 1) writeB(P0, 0);
    S_LGKM0(); S_BAR();
    if (ko < NT - 3) issueB(P0, ko + 3);
    if (ko < NT - 2) stageA(1, ko + 2);
  }

#pragma unroll
  for (int m = 0; m < 4; ++m)
#pragma unroll
    for (int n = 0; n < 4; ++n) {
      int col = n0 + wc * 64 + n * 16 + l15;
#pragma unroll
      for (int j = 0; j < 4; ++j) {
        int row = rt * 128 + wr * 64 + m * 16 + lk * 4 + j;
        if (row < cnt) {
          if (seg == 7) y[(size_t)row * 1024 + col] = acc[m][n][j];
          else          yr[(size_t)(obase + row) * 1024 + col] = acc[m][n][j];
        }
      }
    }
}

// ---------------- combine: y[m] += yr[tokrow[m]] ----------------
__global__ __launch_bounds__(256) void combine_kernel(const float* __restrict__ yr,
                                                      const int* __restrict__ tokrow,
                                                      float* __restrict__ y) {
  int m = blockIdx.x;
  int d = threadIdx.x * 4;
  int r = tokrow[m];
  float4 a = *reinterpret_cast<const float4*>(yr + (size_t)r * 1024 + d);
  float4 o = *reinterpret_cast<const float4*>(y + (size_t)m * 1024 + d);
  o.x += a.x; o.y += a.y; o.z += a.z; o.w += a.w;
  *reinterpret_cast<float4*>(y + (size_t)m * 1024 + d) = o;
}

extern "C" void kernel_launch(void* const* d_in, const int* in_sizes, int n_in,
                              void* d_out, int out_size, void* d_ws, size_t ws_size,
                              hipStream_t stream)
{
  const float* x   = (const float*)d_in[0];   // [2048][1024]
  const float* Wg  = (const float*)d_in[1];   // [1024][8]
  const float* Wl1 = (const float*)d_in[2];   // [8][1024][4096]
  const float* Wl2 = (const float*)d_in[3];   // [8][2048][1024]
  float* y = (float*)d_out;                   // [2048][1024]
  char* ws = (char*)d_ws;

  uint16_t* xbf = (uint16_t*)(ws);                    //  4 MiB
  uint16_t* h   = (uint16_t*)(ws + (4ull  << 20));    // 16 MiB
  float*    yr  = (float*)   (ws + (20ull << 20));    //  8 MiB
  int* idx    = (int*)(ws + (28ull << 20));
  int* tokrow = idx + 2048;
  int* soff   = tokrow + 2048;
  int* scnt   = soff + 8;
  int* rowmap = scnt + 8;  // 2048 ints

  gate_kernel<<<512, 256, 0, stream>>>(x, Wg, xbf, idx);
  compact_kernel<<<1, 256, 0, stream>>>(idx, soff, scnt, rowmap, tokrow);
  ffn1_kernel<<<dim3(32, 58), 256, 0, stream>>>(xbf, Wl1, soff, scnt, rowmap, h);
  ffn2_kernel<<<dim3(8, 58), 256, 0, stream>>>(h, Wl2, soff, scnt, y, yr);
  combine_kernel<<<2048, 256, 0, stream>>>(yr, tokrow, y);
}